// Round 1
// baseline (1250.066 us; speedup 1.0000x reference)
//
#include <hip/hip_runtime.h>
#include <hip/hip_bf16.h>

#define WSZ 7
#define WD  49
#define HD  32
#define NH  8
#define NWIN 64
#define HH  56
#define SS  3
#define TOK 3136   // 56*56
#define EMB 256

// ---------------- Attention kernel: one block per (b, window, head) -------------
__global__ __launch_bounds__(64) void attn_kernel(
    const float* __restrict__ x,      // (B, 3136, 256)
    const float* __restrict__ qkv_w,  // (32, 96) row-major
    const float* __restrict__ qkv_b,  // (96,)
    const float* __restrict__ rpb,    // (169, 8)
    float* __restrict__ o_mid)        // (B, 3136, 256)  un-shifted layout
{
    const int t  = threadIdx.x;
    const int id = blockIdx.x;            // b*NWIN*NH + w*NH + h
    const int h  = id % NH;
    const int w  = (id / NH) % NWIN;
    const int b  = id / (NH * NWIN);
    const int wi = w / 8, wj = w % 8;

    __shared__ float s_x[WD][HD + 1];
    __shared__ float s_q[WD][HD + 1];
    __shared__ float s_k[WD][HD + 1];
    __shared__ float s_v[WD][HD + 1];
    __shared__ float s_w[32 * 96];
    __shared__ float s_b[96];
    __shared__ int   s_reg[WD];
    __shared__ int   s_pos[WD];

    if (t < WD) {
        int ti = t / WSZ, tj = t % WSZ;
        int sh = wi * WSZ + ti;           // shifted-image coords
        int sw = wj * WSZ + tj;
        int rr = (sh < HH - WSZ) ? 0 : (sh < HH - SS) ? 1 : 2;
        int rc = (sw < HH - WSZ) ? 0 : (sw < HH - SS) ? 1 : 2;
        s_reg[t] = rr * 3 + rc;
        int oh = (sh + SS) % HH;          // original-image coords
        int ow = (sw + SS) % HH;
        s_pos[t] = oh * HH + ow;
    }
    for (int i = t; i < 32 * 96; i += 64) s_w[i] = qkv_w[i];
    if (t < 96) s_b[t] = qkv_b[t];        // 64 threads: need loop
    for (int i = t + 64; i < 96; i += 64) s_b[i] = qkv_b[i];
    __syncthreads();

    // load x head slice (49 x 32)
    for (int i = t; i < WD * HD; i += 64) {
        int tok = i >> 5, c = i & 31;
        s_x[tok][c] = x[((size_t)b * TOK + s_pos[tok]) * EMB + h * HD + c];
    }
    __syncthreads();

    // qkv projection: (49x32) @ (32x96) + b
    const float scale = 0.17677669529663687f;   // 1/sqrt(32)
    for (int i = t; i < WD * 96; i += 64) {
        int tok = i / 96, j = i % 96;
        float acc = s_b[j];
        #pragma unroll
        for (int c = 0; c < HD; ++c) acc += s_x[tok][c] * s_w[c * 96 + j];
        if (j < 32)      s_q[tok][j]      = acc * scale;
        else if (j < 64) s_k[tok][j - 32] = acc;
        else             s_v[tok][j - 64] = acc;
    }
    __syncthreads();

    if (t < WD) {
        float qreg[HD];
        #pragma unroll
        for (int c = 0; c < HD; ++c) qreg[c] = s_q[t][c];

        const int qi = t / WSZ, qj = t % WSZ;
        const int myreg = s_reg[t];
        float s[WD];
        float mx = -1e30f;
        #pragma unroll
        for (int j = 0; j < WD; ++j) {
            float acc = 0.f;
            #pragma unroll
            for (int c = 0; c < HD; ++c) acc += qreg[c] * s_k[j][c];
            int ki = j / WSZ, kj = j % WSZ;
            acc += rpb[((qi - ki + 6) * 13 + (qj - kj + 6)) * NH + h];
            if (s_reg[j] != myreg) acc -= 100.f;
            s[j] = acc;
            mx = fmaxf(mx, acc);
        }
        float sum = 0.f;
        #pragma unroll
        for (int j = 0; j < WD; ++j) { s[j] = __expf(s[j] - mx); sum += s[j]; }
        const float inv = 1.f / sum;

        float* op = &o_mid[((size_t)b * TOK + s_pos[t]) * EMB + h * HD];
        #pragma unroll
        for (int c = 0; c < HD; ++c) {
            float acc = 0.f;
            #pragma unroll
            for (int j = 0; j < WD; ++j) acc += s[j] * s_v[j][c];
            op[c] = acc * inv;
        }
    }
}

// ---------------- Projection GEMM: (M,256) @ (256,256) + bias -------------------
__global__ __launch_bounds__(256) void proj_kernel(
    const float* __restrict__ A,     // (M,256)
    const float* __restrict__ Bw,    // (256,256)
    const float* __restrict__ bias,  // (256,)
    float* __restrict__ C, int M)
{
    __shared__ float As[16][64];     // [k][m]
    __shared__ float Bs[16][64];     // [k][n]
    const int tid = threadIdx.x;
    const int tx = tid & 15, ty = tid >> 4;
    const size_t m0 = (size_t)blockIdx.x * 64;
    const int    n0 = blockIdx.y * 64;

    float acc[4][4] = {};
    for (int k0 = 0; k0 < 256; k0 += 16) {
        {
            int m = tid >> 2;                 // 0..63
            int k = (tid & 3) << 2;           // 0,4,8,12
            float4 av = *(const float4*)(A + (m0 + m) * EMB + k0 + k);
            As[k + 0][m] = av.x; As[k + 1][m] = av.y;
            As[k + 2][m] = av.z; As[k + 3][m] = av.w;
            int kk = tid >> 4;                // 0..15
            int n  = (tid & 15) << 2;         // 0..60
            *(float4*)&Bs[kk][n] = *(const float4*)(Bw + (k0 + kk) * EMB + n0 + n);
        }
        __syncthreads();
        #pragma unroll
        for (int k = 0; k < 16; ++k) {
            float a[4], bb[4];
            #pragma unroll
            for (int i = 0; i < 4; ++i) a[i]  = As[k][ty * 4 + i];
            #pragma unroll
            for (int j = 0; j < 4; ++j) bb[j] = Bs[k][tx * 4 + j];
            #pragma unroll
            for (int i = 0; i < 4; ++i)
                #pragma unroll
                for (int j = 0; j < 4; ++j)
                    acc[i][j] += a[i] * bb[j];
        }
        __syncthreads();
    }
    #pragma unroll
    for (int i = 0; i < 4; ++i) {
        size_t m = m0 + ty * 4 + i;
        #pragma unroll
        for (int j = 0; j < 4; ++j) {
            int n = n0 + tx * 4 + j;
            C[m * EMB + n] = acc[i][j] + bias[n];
        }
    }
}

extern "C" void kernel_launch(void* const* d_in, const int* in_sizes, int n_in,
                              void* d_out, int out_size, void* d_ws, size_t ws_size,
                              hipStream_t stream) {
    const float* x      = (const float*)d_in[0];
    const float* qkv_w  = (const float*)d_in[1];
    const float* qkv_b  = (const float*)d_in[2];
    const float* proj_w = (const float*)d_in[3];
    const float* proj_b = (const float*)d_in[4];
    const float* rpb    = (const float*)d_in[5];
    float* out   = (float*)d_out;
    float* o_mid = (float*)d_ws;          // (B,3136,256) fp32 intermediate

    const int B = in_sizes[0] / (TOK * EMB);   // 32
    const int M = B * TOK;                     // 100352

    attn_kernel<<<B * NWIN * NH, 64, 0, stream>>>(x, qkv_w, qkv_b, rpb, o_mid);
    dim3 g(M / 64, EMB / 64);
    proj_kernel<<<g, 256, 0, stream>>>(o_mid, proj_w, proj_b, out, M);
}

// Round 2
// 532.082 us; speedup vs baseline: 2.3494x; 2.3494x over previous
//
#include <hip/hip_runtime.h>
#include <hip/hip_bf16.h>

#define WSZ 7
#define WD  49
#define NH  8
#define NWIN 64
#define HH  56
#define SS  3
#define TOK 3136
#define EMB 256

typedef __attribute__((ext_vector_type(8))) short bf16x8;
typedef __attribute__((ext_vector_type(4))) float f32x4;

// ---- LDS byte offsets (dynamic shared) ----
#define OFF_XW   0                    // 64 x 264 bf16 = 33792 B  (row pad +8 -> 2-way bank max)
#define OFF_WT   33792                // w^T: 96 x 40 bf16 = 7680 B
#define OFF_BIAS 41472                // 96 f32
#define OFF_RPB  41856                // 169*8 f32 = 5408 B
#define OFF_REG  47264                // 64 int
#define OFF_POS  47520                // 64 int
#define OFF_PW   47776                // per-wave scratch x4
#define PW_SZ    14848                // Q(5120)+K(5120) [P(9216) aliases Q..K] + VT(4608)
#define PW_K     5120
#define PW_VT    10240
#define LDS_TOTAL (OFF_PW + 4*PW_SZ) // 107168 B

__device__ __forceinline__ unsigned short f2bf(float f) {
    union { float f; unsigned u; } v; v.f = f;
    return (unsigned short)((v.u + 0x7FFFu + ((v.u >> 16) & 1u)) >> 16);
}
__device__ __forceinline__ unsigned long long pack4(float a, float b, float c, float d) {
    return (unsigned long long)f2bf(a) | ((unsigned long long)f2bf(b) << 16)
         | ((unsigned long long)f2bf(c) << 32) | ((unsigned long long)f2bf(d) << 48);
}

// One block per (b, window): 256 threads = 4 waves, wave w handles heads 2w, 2w+1.
__global__ __launch_bounds__(256, 1) void attn_kernel(
    const float* __restrict__ x, const float* __restrict__ qkv_w,
    const float* __restrict__ qkv_b, const float* __restrict__ rpb,
    float* __restrict__ o_mid)
{
    extern __shared__ char smem[];
    unsigned short* sXW = (unsigned short*)(smem + OFF_XW);
    unsigned short* sWT = (unsigned short*)(smem + OFF_WT);
    float* sBias = (float*)(smem + OFF_BIAS);
    float* sRPB  = (float*)(smem + OFF_RPB);
    int*   sREG  = (int*)(smem + OFF_REG);
    int*   sPOS  = (int*)(smem + OFF_POS);

    const int tid = threadIdx.x;
    const int w = blockIdx.x & 63, b = blockIdx.x >> 6;
    const int wi = w >> 3, wj = w & 7;

    // region + position tables (shifted coords -> original coords)
    if (tid < 64) {
        int ti = tid / 7, tj = tid - (tid / 7) * 7;
        int sh = wi * WSZ + ti, sw = wj * WSZ + tj;
        int rr = (sh < HH - WSZ) ? 0 : (sh < HH - SS) ? 1 : 2;
        int rc = (sw < HH - WSZ) ? 0 : (sw < HH - SS) ? 1 : 2;
        sREG[tid] = rr * 3 + rc;
        sPOS[tid] = ((sh + SS) % HH) * HH + ((sw + SS) % HH);
    }
    // zero padding rows 49..63 of x tile
    for (int i = tid; i < 15 * 264; i += 256) sXW[49 * 264 + i] = 0;
    // stage x window (fp32 -> bf16), coalesced float4 per 64-lane row-group
    {
        const int lane6 = tid & 63, grp = tid >> 6;
        for (int row = grp; row < WD; row += 4) {
            int ti = row / 7, tj = row - ti * 7;
            int oh = (wi * WSZ + ti + SS) % HH, ow = (wj * WSZ + tj + SS) % HH;
            const float4* src = (const float4*)(x + ((size_t)b * TOK + oh * HH + ow) * EMB) + lane6;
            float4 v = *src;
            *(unsigned long long*)(&sXW[row * 264 + lane6 * 4]) = pack4(v.x, v.y, v.z, v.w);
        }
    }
    // qkv weights transposed: sWT[j][c] = qkv_w[c][j]
    for (int i = tid; i < 32 * 96; i += 256) {
        int c = i / 96, j = i - c * 96;
        sWT[j * 40 + c] = f2bf(qkv_w[i]);
    }
    for (int i = tid; i < 96; i += 256) sBias[i] = qkv_b[i];
    for (int i = tid; i < 169 * NH; i += 256) sRPB[i] = rpb[i];
    __syncthreads();   // the only block barrier

    const int wave = tid >> 6, lane = tid & 63;
    const int cl = lane & 15, quad = lane >> 4;
    unsigned short* sQ  = (unsigned short*)(smem + OFF_PW + wave * PW_SZ);
    unsigned short* sK  = sQ + PW_K / 2;
    unsigned short* sVT = sQ + PW_VT / 2;
    unsigned short* sP  = sQ;   // aliases Q+K (dead by then)

    // key-side per-lane tables (kt = nt*16 + cl)
    int ki[4], kj[4], kreg[4];
    #pragma unroll
    for (int nt = 0; nt < 4; ++nt) {
        int kt = nt * 16 + cl;
        ki[nt] = kt / 7; kj[nt] = kt - ki[nt] * 7;
        kreg[nt] = sREG[kt];
    }
    const float qscale = 0.17677669529663687f;  // 1/sqrt(32)

    for (int hi = 0; hi < 2; ++hi) {
        const int h = wave * 2 + hi;
        // ---------- qkv: (64x32) @ (32x96) ----------
        bf16x8 xa[4];
        #pragma unroll
        for (int mt = 0; mt < 4; ++mt)
            xa[mt] = *(const bf16x8*)(&sXW[(mt * 16 + cl) * 264 + h * 32 + quad * 8]);
        #pragma unroll
        for (int nt = 0; nt < 6; ++nt) {
            bf16x8 wb = *(const bf16x8*)(&sWT[(nt * 16 + cl) * 40 + quad * 8]);
            float bias = sBias[nt * 16 + cl];
            #pragma unroll
            for (int mt = 0; mt < 4; ++mt) {
                f32x4 c = {0.f, 0.f, 0.f, 0.f};
                c = __builtin_amdgcn_mfma_f32_16x16x32_bf16(xa[mt], wb, c, 0, 0, 0);
                int tok0 = mt * 16 + quad * 4;
                if (nt < 2) {
                    int col = nt * 16 + cl;
                    #pragma unroll
                    for (int r = 0; r < 4; ++r)
                        sQ[(tok0 + r) * 40 + col] = f2bf((c[r] + bias) * qscale);
                } else if (nt < 4) {
                    int col = nt * 16 + cl - 32;
                    #pragma unroll
                    for (int r = 0; r < 4; ++r)
                        sK[(tok0 + r) * 40 + col] = f2bf(c[r] + bias);
                } else {
                    int hd = nt * 16 + cl - 64;   // V^T[hd][tok], 4 consecutive toks
                    *(unsigned long long*)(&sVT[hd * 72 + tok0]) =
                        pack4(c[0] + bias, c[1] + bias, c[2] + bias, c[3] + bias);
                }
            }
        }
        // ---------- scores: Q @ K^T (64x64, K=32) ----------
        bf16x8 qa[4], kb[4];
        #pragma unroll
        for (int mt = 0; mt < 4; ++mt) qa[mt] = *(const bf16x8*)(&sQ[(mt * 16 + cl) * 40 + quad * 8]);
        #pragma unroll
        for (int nt = 0; nt < 4; ++nt) kb[nt] = *(const bf16x8*)(&sK[(nt * 16 + cl) * 40 + quad * 8]);
        f32x4 sc[4][4];
        #pragma unroll
        for (int mt = 0; mt < 4; ++mt)
            #pragma unroll
            for (int nt = 0; nt < 4; ++nt) {
                f32x4 z = {0.f, 0.f, 0.f, 0.f};
                sc[mt][nt] = __builtin_amdgcn_mfma_f32_16x16x32_bf16(qa[mt], kb[nt], z, 0, 0, 0);
            }
        // ---------- softmax (no max pass: |score| bounded ~10) + write P ----------
        #pragma unroll
        for (int mt = 0; mt < 4; ++mt) {
            #pragma unroll
            for (int r = 0; r < 4; ++r) {
                int qt = mt * 16 + quad * 4 + r;
                int qi = qt / 7, qj = qt - qi * 7;
                int qreg = sREG[qt];
                float pv[4], sm = 0.f;
                #pragma unroll
                for (int nt = 0; nt < 4; ++nt) {
                    int kt = nt * 16 + cl;
                    float v = sc[mt][nt][r];
                    int idx = (qi - ki[nt] + 6) * 13 + (qj - kj[nt] + 6);
                    idx = idx < 0 ? 0 : (idx > 168 ? 168 : idx);
                    v += sRPB[idx * NH + h];
                    if (kreg[nt] != qreg) v -= 100.f;
                    if (kt >= WD) v = -1e30f;     // key padding -> exp == 0
                    v = __expf(v);
                    pv[nt] = v; sm += v;
                }
                sm += __shfl_xor(sm, 1, 16);
                sm += __shfl_xor(sm, 2, 16);
                sm += __shfl_xor(sm, 4, 16);
                sm += __shfl_xor(sm, 8, 16);
                float inv = 1.f / sm;
                #pragma unroll
                for (int nt = 0; nt < 4; ++nt)
                    sP[qt * 72 + nt * 16 + cl] = f2bf(pv[nt] * inv);
            }
        }
        // ---------- PV as O^T = V^T @ P^T (M=32 hd, N=64 qt, K=64 keys) ----------
        f32x4 ot[2][4];
        #pragma unroll
        for (int mv = 0; mv < 2; ++mv)
            #pragma unroll
            for (int nt = 0; nt < 4; ++nt) ot[mv][nt] = (f32x4){0.f, 0.f, 0.f, 0.f};
        #pragma unroll
        for (int ks = 0; ks < 2; ++ks) {
            bf16x8 va[2], pb[4];
            #pragma unroll
            for (int mv = 0; mv < 2; ++mv)
                va[mv] = *(const bf16x8*)(&sVT[(mv * 16 + cl) * 72 + ks * 32 + quad * 8]);
            #pragma unroll
            for (int nt = 0; nt < 4; ++nt)
                pb[nt] = *(const bf16x8*)(&sP[(nt * 16 + cl) * 72 + ks * 32 + quad * 8]);
            #pragma unroll
            for (int mv = 0; mv < 2; ++mv)
                #pragma unroll
                for (int nt = 0; nt < 4; ++nt)
                    ot[mv][nt] = __builtin_amdgcn_mfma_f32_16x16x32_bf16(va[mv], pb[nt], ot[mv][nt], 0, 0, 0);
        }
        // store O rows (qt < 49): 4 consecutive hd per frag reg -> float4
        #pragma unroll
        for (int nt = 0; nt < 4; ++nt) {
            int qt = nt * 16 + cl;
            if (qt < WD) {
                int pos = sPOS[qt];
                float* dst = o_mid + ((size_t)b * TOK + pos) * EMB + h * 32 + quad * 4;
                *(f32x4*)(dst)      = ot[0][nt];
                *(f32x4*)(dst + 16) = ot[1][nt];
            }
        }
    }
}

// ---------------- Projection GEMM: (M,256) @ (256,256) + bias (unchanged) -------
__global__ __launch_bounds__(256) void proj_kernel(
    const float* __restrict__ A, const float* __restrict__ Bw,
    const float* __restrict__ bias, float* __restrict__ C, int M)
{
    __shared__ float As[16][64];
    __shared__ float Bs[16][64];
    const int tid = threadIdx.x;
    const int tx = tid & 15, ty = tid >> 4;
    const size_t m0 = (size_t)blockIdx.x * 64;
    const int    n0 = blockIdx.y * 64;

    float acc[4][4] = {};
    for (int k0 = 0; k0 < 256; k0 += 16) {
        {
            int m = tid >> 2;
            int k = (tid & 3) << 2;
            float4 av = *(const float4*)(A + (m0 + m) * EMB + k0 + k);
            As[k + 0][m] = av.x; As[k + 1][m] = av.y;
            As[k + 2][m] = av.z; As[k + 3][m] = av.w;
            int kk = tid >> 4;
            int n  = (tid & 15) << 2;
            *(float4*)&Bs[kk][n] = *(const float4*)(Bw + (k0 + kk) * EMB + n0 + n);
        }
        __syncthreads();
        #pragma unroll
        for (int k = 0; k < 16; ++k) {
            float a[4], bb[4];
            #pragma unroll
            for (int i = 0; i < 4; ++i) a[i]  = As[k][ty * 4 + i];
            #pragma unroll
            for (int j = 0; j < 4; ++j) bb[j] = Bs[k][tx * 4 + j];
            #pragma unroll
            for (int i = 0; i < 4; ++i)
                #pragma unroll
                for (int j = 0; j < 4; ++j)
                    acc[i][j] += a[i] * bb[j];
        }
        __syncthreads();
    }
    #pragma unroll
    for (int i = 0; i < 4; ++i) {
        size_t m = m0 + ty * 4 + i;
        #pragma unroll
        for (int j = 0; j < 4; ++j) {
            int n = n0 + tx * 4 + j;
            C[m * EMB + n] = acc[i][j] + bias[n];
        }
    }
}

extern "C" void kernel_launch(void* const* d_in, const int* in_sizes, int n_in,
                              void* d_out, int out_size, void* d_ws, size_t ws_size,
                              hipStream_t stream) {
    const float* x      = (const float*)d_in[0];
    const float* qkv_w  = (const float*)d_in[1];
    const float* qkv_b  = (const float*)d_in[2];
    const float* proj_w = (const float*)d_in[3];
    const float* proj_b = (const float*)d_in[4];
    const float* rpb    = (const float*)d_in[5];
    float* out   = (float*)d_out;
    float* o_mid = (float*)d_ws;

    const int B = in_sizes[0] / (TOK * EMB);
    const int M = B * TOK;

    (void)hipFuncSetAttribute(reinterpret_cast<const void*>(&attn_kernel),
                              hipFuncAttributeMaxDynamicSharedMemorySize, LDS_TOTAL);
    attn_kernel<<<B * NWIN, 256, LDS_TOTAL, stream>>>(x, qkv_w, qkv_b, rpb, o_mid);
    dim3 g(M / 64, EMB / 64);
    proj_kernel<<<g, 256, 0, stream>>>(o_mid, proj_w, proj_b, out, M);
}

// Round 3
// 290.903 us; speedup vs baseline: 4.2972x; 1.8291x over previous
//
#include <hip/hip_runtime.h>
#include <hip/hip_bf16.h>

#define WSZ 7
#define WD  49
#define NH  8
#define NWIN 64
#define HH  56
#define SS  3
#define TOK 3136
#define EMB 256

typedef __attribute__((ext_vector_type(8))) short bf16x8;
typedef __attribute__((ext_vector_type(8))) unsigned short u16x8;
typedef __attribute__((ext_vector_type(4))) float f32x4;

// ---- attn LDS layout (dynamic shared, 73376 B -> 2 blocks/CU) ----
#define OFF_WT   0                     // w^T: 96 x 40 bf16 = 7680
#define OFF_BIAS 7680                  // 96 f32
#define OFF_RPB  8064                  // 169*8 f32 = 5408
#define OFF_REG  13472                 // 64 int
#define OFF_POS  13728                 // 64 int
#define OFF_PW   13984                 // per-wave scratch x4
#define PW_SZ    14848                 // Q(5120)+K(5120) [P(9216) aliases] + VT(4608)
#define PW_K     5120
#define PW_VT    10240
#define LDS_TOTAL (OFF_PW + 4*PW_SZ)   // 73376

__device__ __forceinline__ unsigned short f2bf(float f) {
    union { float f; unsigned u; } v; v.f = f;
    return (unsigned short)((v.u + 0x7FFFu + ((v.u >> 16) & 1u)) >> 16);
}
__device__ __forceinline__ unsigned long long pack4(float a, float b, float c, float d) {
    return (unsigned long long)f2bf(a) | ((unsigned long long)f2bf(b) << 16)
         | ((unsigned long long)f2bf(c) << 32) | ((unsigned long long)f2bf(d) << 48);
}

// One block per (b, window): 4 waves, wave w handles heads 2w, 2w+1.
__global__ __launch_bounds__(256, 1) void attn_kernel(
    const float* __restrict__ x, const float* __restrict__ qkv_w,
    const float* __restrict__ qkv_b, const float* __restrict__ rpb,
    unsigned short* __restrict__ o_mid)   // (B,3136,256) bf16, un-shifted layout
{
    extern __shared__ char smem[];
    unsigned short* sWT = (unsigned short*)(smem + OFF_WT);
    float* sBias = (float*)(smem + OFF_BIAS);
    float* sRPB  = (float*)(smem + OFF_RPB);
    int*   sREG  = (int*)(smem + OFF_REG);
    int*   sPOS  = (int*)(smem + OFF_POS);

    const int tid = threadIdx.x;
    const int w = blockIdx.x & 63, b = blockIdx.x >> 6;
    const int wi = w >> 3, wj = w & 7;

    if (tid < 64) {
        int ti = tid / 7, tj = tid - (tid / 7) * 7;
        int sh = wi * WSZ + ti, sw = wj * WSZ + tj;
        int rr = (sh < HH - WSZ) ? 0 : (sh < HH - SS) ? 1 : 2;
        int rc = (sw < HH - WSZ) ? 0 : (sw < HH - SS) ? 1 : 2;
        sREG[tid] = rr * 3 + rc;
        sPOS[tid] = ((sh + SS) % HH) * HH + ((sw + SS) % HH);
    }
    for (int i = tid; i < 32 * 96; i += 256) {
        int c = i / 96, j = i - c * 96;
        sWT[j * 40 + c] = f2bf(qkv_w[i]);
    }
    for (int i = tid; i < 96; i += 256) sBias[i] = qkv_b[i];
    for (int i = tid; i < 169 * NH; i += 256) sRPB[i] = rpb[i];
    __syncthreads();   // only block barrier

    const int wave = tid >> 6, lane = tid & 63;
    const int cl = lane & 15, quad = lane >> 4;
    unsigned short* sQ  = (unsigned short*)(smem + OFF_PW + wave * PW_SZ);
    unsigned short* sK  = sQ + PW_K / 2;
    unsigned short* sVT = sQ + PW_VT / 2;
    unsigned short* sP  = sQ;   // aliases Q+K (dead by then)

    // per-mt x row pointers (tok = mt*16+cl; rows >= 49 load harmless real data,
    // they are masked out downstream: padded keys -> exp(-1e30)=0, padded q -> not stored)
    const float* xrow[4];
    #pragma unroll
    for (int mt = 0; mt < 4; ++mt) {
        int tok = mt * 16 + cl;
        xrow[mt] = x + ((size_t)b * TOK + sPOS[tok]) * EMB + quad * 8;
    }
    int ki[4], kj[4], kreg[4];
    #pragma unroll
    for (int nt = 0; nt < 4; ++nt) {
        int kt = nt * 16 + cl;
        ki[nt] = kt / 7; kj[nt] = kt - ki[nt] * 7;
        kreg[nt] = sREG[kt];
    }
    const float qscale = 0.17677669529663687f;  // 1/sqrt(32)

    #pragma unroll
    for (int hi = 0; hi < 2; ++hi) {
        const int h = wave * 2 + hi;
        // ---------- qkv: (64x32) @ (32x96), A-frags straight from global ----------
        bf16x8 xa[4];
        #pragma unroll
        for (int mt = 0; mt < 4; ++mt) {
            const float* p = xrow[mt] + h * 32;
            float4 v0 = *(const float4*)p, v1 = *(const float4*)(p + 4);
            union { bf16x8 v; unsigned long long q[2]; } u;
            u.q[0] = pack4(v0.x, v0.y, v0.z, v0.w);
            u.q[1] = pack4(v1.x, v1.y, v1.z, v1.w);
            xa[mt] = u.v;
        }
        #pragma unroll
        for (int nt = 0; nt < 6; ++nt) {
            bf16x8 wb = *(const bf16x8*)(&sWT[(nt * 16 + cl) * 40 + quad * 8]);
            float bias = sBias[nt * 16 + cl];
            #pragma unroll
            for (int mt = 0; mt < 4; ++mt) {
                f32x4 c = {bias, bias, bias, bias};
                c = __builtin_amdgcn_mfma_f32_16x16x32_bf16(xa[mt], wb, c, 0, 0, 0);
                int tok0 = mt * 16 + quad * 4;
                if (nt < 2) {
                    int col = nt * 16 + cl;
                    #pragma unroll
                    for (int r = 0; r < 4; ++r)
                        sQ[(tok0 + r) * 40 + col] = f2bf(c[r] * qscale);
                } else if (nt < 4) {
                    int col = nt * 16 + cl - 32;
                    #pragma unroll
                    for (int r = 0; r < 4; ++r)
                        sK[(tok0 + r) * 40 + col] = f2bf(c[r]);
                } else {
                    int hd = nt * 16 + cl - 64;   // V^T[hd][tok]
                    *(unsigned long long*)(&sVT[hd * 72 + tok0]) =
                        pack4(c[0], c[1], c[2], c[3]);
                }
            }
        }
        // ---------- scores: Q @ K^T (64x64, K=32) ----------
        bf16x8 qa[4], kb[4];
        #pragma unroll
        for (int mt = 0; mt < 4; ++mt) qa[mt] = *(const bf16x8*)(&sQ[(mt * 16 + cl) * 40 + quad * 8]);
        #pragma unroll
        for (int nt = 0; nt < 4; ++nt) kb[nt] = *(const bf16x8*)(&sK[(nt * 16 + cl) * 40 + quad * 8]);
        f32x4 sc[4][4];
        #pragma unroll
        for (int mt = 0; mt < 4; ++mt)
            #pragma unroll
            for (int nt = 0; nt < 4; ++nt) {
                f32x4 z = {0.f, 0.f, 0.f, 0.f};
                sc[mt][nt] = __builtin_amdgcn_mfma_f32_16x16x32_bf16(qa[mt], kb[nt], z, 0, 0, 0);
            }
        // ---------- softmax (scores bounded, no max pass) + write P ----------
        #pragma unroll
        for (int mt = 0; mt < 4; ++mt) {
            #pragma unroll
            for (int r = 0; r < 4; ++r) {
                int qt = mt * 16 + quad * 4 + r;
                int qi = qt / 7, qj = qt - qi * 7;
                int qreg = sREG[qt];
                float pv[4], sm = 0.f;
                #pragma unroll
                for (int nt = 0; nt < 4; ++nt) {
                    int kt = nt * 16 + cl;
                    float v = sc[mt][nt][r];
                    int idx = (qi - ki[nt] + 6) * 13 + (qj - kj[nt] + 6);
                    idx = idx < 0 ? 0 : (idx > 168 ? 168 : idx);
                    v += sRPB[idx * NH + h];
                    if (kreg[nt] != qreg) v -= 100.f;
                    if (kt >= WD) v = -1e30f;
                    v = __expf(v);
                    pv[nt] = v; sm += v;
                }
                sm += __shfl_xor(sm, 1, 16);
                sm += __shfl_xor(sm, 2, 16);
                sm += __shfl_xor(sm, 4, 16);
                sm += __shfl_xor(sm, 8, 16);
                float inv = 1.f / sm;
                #pragma unroll
                for (int nt = 0; nt < 4; ++nt)
                    sP[qt * 72 + nt * 16 + cl] = f2bf(pv[nt] * inv);
            }
        }
        // ---------- PV as O^T = V^T @ P^T ----------
        f32x4 ot[2][4];
        #pragma unroll
        for (int mv = 0; mv < 2; ++mv)
            #pragma unroll
            for (int nt = 0; nt < 4; ++nt) ot[mv][nt] = (f32x4){0.f, 0.f, 0.f, 0.f};
        #pragma unroll
        for (int ks = 0; ks < 2; ++ks) {
            bf16x8 va[2], pb[4];
            #pragma unroll
            for (int mv = 0; mv < 2; ++mv)
                va[mv] = *(const bf16x8*)(&sVT[(mv * 16 + cl) * 72 + ks * 32 + quad * 8]);
            #pragma unroll
            for (int nt = 0; nt < 4; ++nt)
                pb[nt] = *(const bf16x8*)(&sP[(nt * 16 + cl) * 72 + ks * 32 + quad * 8]);
            #pragma unroll
            for (int mv = 0; mv < 2; ++mv)
                #pragma unroll
                for (int nt = 0; nt < 4; ++nt)
                    ot[mv][nt] = __builtin_amdgcn_mfma_f32_16x16x32_bf16(va[mv], pb[nt], ot[mv][nt], 0, 0, 0);
        }
        // store O rows (qt < 49) as bf16
        #pragma unroll
        for (int nt = 0; nt < 4; ++nt) {
            int qt = nt * 16 + cl;
            if (qt < WD) {
                int pos = sPOS[qt];
                unsigned short* dst = o_mid + ((size_t)b * TOK + pos) * EMB + h * 32 + quad * 4;
                *(unsigned long long*)(dst)      = pack4(ot[0][nt][0], ot[0][nt][1], ot[0][nt][2], ot[0][nt][3]);
                *(unsigned long long*)(dst + 16) = pack4(ot[1][nt][0], ot[1][nt][1], ot[1][nt][2], ot[1][nt][3]);
            }
        }
    }
}

// ---------------- proj_w fp32 -> bf16 transpose: Wt[n][k] = bf16(W[k][n]) ------
__global__ __launch_bounds__(256) void cvt_kernel(
    const float* __restrict__ W, unsigned short* __restrict__ Wt)
{
    int i = blockIdx.x * 256 + threadIdx.x;     // 65536 elems
    int k = i >> 8, n = i & 255;
    Wt[n * 256 + k] = f2bf(W[i]);
}

// ---------------- Projection GEMM: bf16 MFMA, 128x128 tile, 4 waves ------------
__global__ __launch_bounds__(256) void proj_kernel(
    const unsigned short* __restrict__ A,   // (M,256) bf16
    const unsigned short* __restrict__ Wt,  // (256 n,256 k) bf16
    const float* __restrict__ bias, float* __restrict__ C, int M)
{
    alignas(16) __shared__ unsigned short sA[128 * 32];
    alignas(16) __shared__ unsigned short sB[128 * 32];
    const int tid = threadIdx.x;
    const int wave = tid >> 6, lane = tid & 63;
    const int cl = lane & 15, quad = lane >> 4;
    const int wx = wave & 1, wy = wave >> 1;     // 2x2 wave grid, 64x64 each
    const size_t m0 = (size_t)blockIdx.x * 128;
    const int n0 = blockIdx.y * 128;

    float bias_r[4];
    #pragma unroll
    for (int nt = 0; nt < 4; ++nt) bias_r[nt] = bias[n0 + wx * 64 + nt * 16 + cl];

    f32x4 acc[4][4];
    #pragma unroll
    for (int mt = 0; mt < 4; ++mt)
        #pragma unroll
        for (int nt = 0; nt < 4; ++nt) acc[mt][nt] = (f32x4){0.f, 0.f, 0.f, 0.f};

    for (int k0 = 0; k0 < 256; k0 += 32) {
        #pragma unroll
        for (int s = 0; s < 2; ++s) {
            int c = s * 256 + tid;              // 512 chunks of 16B
            int row = c >> 2, ch = c & 3;
            *(u16x8*)(sA + row * 32 + ch * 8) = *(const u16x8*)(A  + (m0 + row) * 256 + k0 + ch * 8);
            *(u16x8*)(sB + row * 32 + ch * 8) = *(const u16x8*)(Wt + (size_t)(n0 + row) * 256 + k0 + ch * 8);
        }
        __syncthreads();
        bf16x8 af[4], bf[4];
        #pragma unroll
        for (int mt = 0; mt < 4; ++mt) af[mt] = *(const bf16x8*)(&sA[(wy * 64 + mt * 16 + cl) * 32 + quad * 8]);
        #pragma unroll
        for (int nt = 0; nt < 4; ++nt) bf[nt] = *(const bf16x8*)(&sB[(wx * 64 + nt * 16 + cl) * 32 + quad * 8]);
        #pragma unroll
        for (int mt = 0; mt < 4; ++mt)
            #pragma unroll
            for (int nt = 0; nt < 4; ++nt)
                acc[mt][nt] = __builtin_amdgcn_mfma_f32_16x16x32_bf16(af[mt], bf[nt], acc[mt][nt], 0, 0, 0);
        __syncthreads();
    }
    #pragma unroll
    for (int mt = 0; mt < 4; ++mt)
        #pragma unroll
        for (int nt = 0; nt < 4; ++nt) {
            #pragma unroll
            for (int r = 0; r < 4; ++r) {
                size_t m = m0 + wy * 64 + mt * 16 + quad * 4 + r;
                int n = n0 + wx * 64 + nt * 16 + cl;
                C[m * 256 + n] = acc[mt][nt][r] + bias_r[nt];
            }
        }
}

extern "C" void kernel_launch(void* const* d_in, const int* in_sizes, int n_in,
                              void* d_out, int out_size, void* d_ws, size_t ws_size,
                              hipStream_t stream) {
    const float* x      = (const float*)d_in[0];
    const float* qkv_w  = (const float*)d_in[1];
    const float* qkv_b  = (const float*)d_in[2];
    const float* proj_w = (const float*)d_in[3];
    const float* proj_b = (const float*)d_in[4];
    const float* rpb    = (const float*)d_in[5];
    float* out = (float*)d_out;

    const int B = in_sizes[0] / (TOK * EMB);
    const int M = B * TOK;

    unsigned short* o_mid = (unsigned short*)d_ws;                       // M*256 bf16
    unsigned short* Wt    = (unsigned short*)((char*)d_ws + (size_t)M * EMB * 2);

    (void)hipFuncSetAttribute(reinterpret_cast<const void*>(&attn_kernel),
                              hipFuncAttributeMaxDynamicSharedMemorySize, LDS_TOTAL);
    cvt_kernel<<<256, 256, 0, stream>>>(proj_w, Wt);
    attn_kernel<<<B * NWIN, 256, LDS_TOTAL, stream>>>(x, qkv_w, qkv_b, rpb, o_mid);
    dim3 g(M / 128, EMB / 128);
    proj_kernel<<<g, 256, 0, stream>>>(o_mid, Wt, proj_b, out, M);
}